// Round 1
// baseline (586.074 us; speedup 1.0000x reference)
//
#include <hip/hip_runtime.h>
#include <hip/hip_bf16.h>
#include <stdint.h>

#define TOKENS 8192
#define HD     2048
#define NE     8

typedef __attribute__((ext_vector_type(8))) short short8;
typedef __attribute__((ext_vector_type(4))) float f32x4;

__device__ __forceinline__ unsigned short f2bf_rne(float f) {
  union { float f; unsigned u; } v; v.f = f;
  unsigned u = v.u;
  return (unsigned short)((u + 0x7fffu + ((u >> 16) & 1u)) >> 16);
}

__device__ __forceinline__ void async_load16(const void* g, void* lds) {
  __builtin_amdgcn_global_load_lds(
      (const __attribute__((address_space(1))) unsigned int*)g,
      (__attribute__((address_space(3))) unsigned int*)lds, 16, 0, 0);
}

// ---------------------------------------------------------------- convert W
__global__ void convert_w_kernel(const float* __restrict__ src,
                                 unsigned short* __restrict__ dst, int n4) {
  int i = blockIdx.x * blockDim.x + threadIdx.x;
  int stride = gridDim.x * blockDim.x;
  const float4* s4 = (const float4*)src;
  ushort4* d4 = (ushort4*)dst;
  for (; i < n4; i += stride) {
    float4 v = s4[i];
    ushort4 o;
    o.x = f2bf_rne(v.x); o.y = f2bf_rne(v.y);
    o.z = f2bf_rne(v.z); o.w = f2bf_rne(v.w);
    d4[i] = o;
  }
}

// ---------------------------------------------------------------- router
// wave-per-token: fp32 logits (exact, written to d_out), softmax+top2+renorm,
// bucket (expert -> token list) via padded atomic counters; fused x->bf16.
__global__ __launch_bounds__(256) void router_kernel(
    const float* __restrict__ x, const float* __restrict__ gw,
    unsigned short* __restrict__ xb, float* __restrict__ logits_out,
    int* __restrict__ counts, int* __restrict__ btok, float* __restrict__ bwt) {
  const int wid  = threadIdx.x >> 6;
  const int lane = threadIdx.x & 63;
  const int t = blockIdx.x * 4 + wid;

  const float4* xr = (const float4*)(x + (size_t)t * HD);
  const float4* g4 = (const float4*)gw;
  ushort4* xb4 = (ushort4*)(xb + (size_t)t * HD);

  float acc[NE];
#pragma unroll
  for (int e = 0; e < NE; ++e) acc[e] = 0.f;

#pragma unroll
  for (int it = 0; it < 8; ++it) {
    int idx = it * 64 + lane;
    float4 v = xr[idx];
    ushort4 o;
    o.x = f2bf_rne(v.x); o.y = f2bf_rne(v.y);
    o.z = f2bf_rne(v.z); o.w = f2bf_rne(v.w);
    xb4[idx] = o;
#pragma unroll
    for (int e = 0; e < NE; ++e) {
      float4 g = g4[e * 512 + idx];
      acc[e] += v.x * g.x + v.y * g.y + v.z * g.z + v.w * g.w;
    }
  }
#pragma unroll
  for (int e = 0; e < NE; ++e) {
#pragma unroll
    for (int off = 32; off > 0; off >>= 1)
      acc[e] += __shfl_xor(acc[e], off, 64);
  }
  if (lane == 0) {
    float* lo = logits_out + (size_t)t * NE;
    float m = acc[0];
#pragma unroll
    for (int e = 1; e < NE; ++e) m = fmaxf(m, acc[e]);
    float p[NE];
#pragma unroll
    for (int e = 0; e < NE; ++e) { p[e] = expf(acc[e] - m); lo[e] = acc[e]; }
    int i0 = 0; float b0 = p[0];
#pragma unroll
    for (int e = 1; e < NE; ++e) if (p[e] > b0) { b0 = p[e]; i0 = e; }
    int i1 = -1; float b1 = -1.f;
#pragma unroll
    for (int e = 0; e < NE; ++e) if (e != i0 && p[e] > b1) { b1 = p[e]; i1 = e; }
    float inv = 1.f / (b0 + b1);
    int pos0 = atomicAdd(&counts[i0 * 32], 1);  // counters padded 128B apart
    btok[i0 * TOKENS + pos0] = t; bwt[i0 * TOKENS + pos0] = b0 * inv;
    int pos1 = atomicAdd(&counts[i1 * 32], 1);
    btok[i1 * TOKENS + pos1] = t; bwt[i1 * TOKENS + pos1] = b1 * inv;
  }
}

// ---------------------------------------------------------------- MoE GEMM
// Per (expert, rowtile, coltile): Y = gather(Xbf16) @ We^T, 128x128 tile,
// BK=64, mfma_f32_16x16x32_bf16, global_load_lds(16B) staging with XOR
// swizzle (chunk ^ (row&7)) so frag ds_read_b128 is 2-way-only (free, m136).
__global__ __launch_bounds__(256, 2) void moe_gemm_kernel(
    const unsigned short* __restrict__ xb,
    const unsigned short* __restrict__ wb,
    const int* __restrict__ counts,
    const int* __restrict__ btok,
    const float* __restrict__ bwt,
    float* __restrict__ out) {
  const int rowtile = blockIdx.x;
  const int coltile = blockIdx.y;
  const int e       = blockIdx.z;
  const int cnt = counts[e * 32];
  if (rowtile * 128 >= cnt) return;

  __shared__ unsigned short As[128 * 64];
  __shared__ unsigned short Bs[128 * 64];
  __shared__ int   tok_s[128];
  __shared__ float w_s[128];

  const int tid  = threadIdx.x;
  const int wid  = tid >> 6;
  const int lane = tid & 63;

  if (tid < 128) {
    int r  = rowtile * 128 + tid;
    int rc = r < cnt ? r : cnt - 1;   // clamp pad rows to a valid token
    tok_s[tid] = btok[e * TOKENS + rc];
    w_s[tid]   = bwt[e * TOKENS + rc];
  }
  __syncthreads();

  // staging: 1024 16B slots per tile; slot = wid*256 + it*64 + lane
  // LDS slot (row, cs) holds data chunk cs ^ (row&7)
  int a_off[4], b_off[4];
#pragma unroll
  for (int it = 0; it < 4; ++it) {
    int slot = wid * 256 + it * 64 + lane;
    int row  = slot >> 3;
    int ch   = (slot & 7) ^ (row & 7);
    a_off[it] = tok_s[row] * HD + ch * 8;
    b_off[it] = (e * HD + coltile * 128 + row) * HD + ch * 8;
  }

  f32x4 acc[4][4];
#pragma unroll
  for (int i = 0; i < 4; ++i)
#pragma unroll
    for (int j = 0; j < 4; ++j) acc[i][j] = (f32x4){0.f, 0.f, 0.f, 0.f};

  const int quad = lane >> 4;
  const int mrow = lane & 15;
  const int wm2  = wid >> 1;
  const int wn2  = wid & 1;

  int a_rd[2][4], b_rd[2][4];
#pragma unroll
  for (int h = 0; h < 2; ++h)
#pragma unroll
    for (int i = 0; i < 4; ++i) {
      int ra = wm2 * 64 + i * 16 + mrow;
      a_rd[h][i] = ra * 64 + ((4 * h + quad) ^ (ra & 7)) * 8;
      int rb = wn2 * 64 + i * 16 + mrow;
      b_rd[h][i] = rb * 64 + ((4 * h + quad) ^ (rb & 7)) * 8;
    }

  for (int k0 = 0; k0 < HD; k0 += 64) {
#pragma unroll
    for (int it = 0; it < 4; ++it) {
      async_load16(xb + a_off[it] + k0, &As[(wid * 256 + it * 64) * 8]);
      async_load16(wb + b_off[it] + k0, &Bs[(wid * 256 + it * 64) * 8]);
    }
    __syncthreads();   // compiler drains vmcnt(0) before s_barrier
#pragma unroll
    for (int h = 0; h < 2; ++h) {
      short8 fa[4], fb[4];
#pragma unroll
      for (int i = 0; i < 4; ++i) {
        fa[i] = *(const short8*)&As[a_rd[h][i]];
        fb[i] = *(const short8*)&Bs[b_rd[h][i]];
      }
#pragma unroll
      for (int i = 0; i < 4; ++i)
#pragma unroll
        for (int j = 0; j < 4; ++j)
          acc[i][j] = __builtin_amdgcn_mfma_f32_16x16x32_bf16(
              fa[i], fb[j], acc[i][j], 0, 0, 0);
    }
    __syncthreads();
  }

  // epilogue: D layout col=lane&15, row=quad*4+r (m89/m91). Scale by routing
  // weight; each out element receives exactly 2 adds (two experts) -> atomic.
#pragma unroll
  for (int i = 0; i < 4; ++i)
#pragma unroll
    for (int j = 0; j < 4; ++j)
#pragma unroll
      for (int r = 0; r < 4; ++r) {
        int m = wm2 * 64 + i * 16 + quad * 4 + r;
        if (rowtile * 128 + m < cnt) {
          int n = coltile * 128 + wn2 * 64 + j * 16 + mrow;
          unsafeAtomicAdd(out + (size_t)tok_s[m] * HD + n,
                          w_s[m] * acc[i][j][r]);
        }
      }
}

// ---------------------------------------------------------------- launch
extern "C" void kernel_launch(void* const* d_in, const int* in_sizes, int n_in,
                              void* d_out, int out_size, void* d_ws, size_t ws_size,
                              hipStream_t stream) {
  const float* x  = (const float*)d_in[0];   // [8192, 2048]
  const float* gw = (const float*)d_in[1];   // [8, 2048]
  const float* ew = (const float*)d_in[2];   // [8, 2048, 2048]
  float* out = (float*)d_out;                // [8192*2048] + [8192*8]

  char* ws = (char*)d_ws;
  unsigned short* xb = (unsigned short*)ws;                         // 33,554,432 B
  unsigned short* wb = (unsigned short*)(ws + 33554432u);           // 67,108,864 B
  int*   counts = (int*)(ws + 33554432u + 67108864u);               // 1,024 B (padded)
  int*   btok   = (int*)(ws + 33554432u + 67108864u + 1024u);       // 262,144 B
  float* bwt    = (float*)(ws + 33554432u + 67108864u + 1024u + 262144u); // 262,144 B
  // total ws use: ~101.2 MB

  hipMemsetAsync(out, 0, (size_t)TOKENS * HD * sizeof(float), stream);
  hipMemsetAsync(counts, 0, 1024, stream);
  convert_w_kernel<<<8192, 256, 0, stream>>>(ew, wb, NE * HD * HD / 4);
  router_kernel<<<TOKENS / 4, 256, 0, stream>>>(
      x, gw, xb, out + (size_t)TOKENS * HD, counts, btok, bwt);
  moe_gemm_kernel<<<dim3(64, 16, 8), 256, 0, stream>>>(
      xb, wb, counts, btok, bwt, out);
}

// Round 2
// 496.056 us; speedup vs baseline: 1.1815x; 1.1815x over previous
//
#include <hip/hip_runtime.h>
#include <hip/hip_bf16.h>
#include <stdint.h>

#define TOKENS 8192
#define HD     2048
#define NE     8

typedef __attribute__((ext_vector_type(8))) short short8;
typedef __attribute__((ext_vector_type(8))) unsigned short ushort8v;
typedef __attribute__((ext_vector_type(4))) float f32x4;

__device__ __forceinline__ unsigned short f2bf_rne(float f) {
  union { float f; unsigned u; } v; v.f = f;
  unsigned u = v.u;
  return (unsigned short)((u + 0x7fffu + ((u >> 16) & 1u)) >> 16);
}

__device__ __forceinline__ void async_load16(const void* g, void* lds) {
  __builtin_amdgcn_global_load_lds(
      (const __attribute__((address_space(1))) unsigned int*)g,
      (__attribute__((address_space(3))) unsigned int*)lds, 16, 0, 0);
}

// ---------------------------------------------------------------- convert W
// fp32 -> bf16, 2x float4 in, 1x 16B out per thread-iter.
__global__ void convert_w_kernel(const float* __restrict__ src,
                                 unsigned short* __restrict__ dst, int n8) {
  int i = blockIdx.x * blockDim.x + threadIdx.x;
  int stride = gridDim.x * blockDim.x;
  const float4* s4 = (const float4*)src;
  ushort8v* d8 = (ushort8v*)dst;
  for (; i < n8; i += stride) {
    float4 a = s4[i * 2], b = s4[i * 2 + 1];
    ushort8v o;
    o[0] = f2bf_rne(a.x); o[1] = f2bf_rne(a.y);
    o[2] = f2bf_rne(a.z); o[3] = f2bf_rne(a.w);
    o[4] = f2bf_rne(b.x); o[5] = f2bf_rne(b.y);
    o[6] = f2bf_rne(b.z); o[7] = f2bf_rne(b.w);
    d8[i] = o;
  }
}

// ---------------------------------------------------------------- router
// wave-per-token: fp32 logits (exact) -> d_out; fused x -> bf16. NO atomics.
__global__ __launch_bounds__(256) void router_kernel(
    const float* __restrict__ x, const float* __restrict__ gw,
    unsigned short* __restrict__ xb, float* __restrict__ logits_out) {
  const int wid  = threadIdx.x >> 6;
  const int lane = threadIdx.x & 63;
  const int t = blockIdx.x * 4 + wid;

  const float4* xr = (const float4*)(x + (size_t)t * HD);
  const float4* g4 = (const float4*)gw;
  ushort4* xb4 = (ushort4*)(xb + (size_t)t * HD);

  float acc[NE];
#pragma unroll
  for (int e = 0; e < NE; ++e) acc[e] = 0.f;

#pragma unroll
  for (int it = 0; it < 8; ++it) {
    int idx = it * 64 + lane;
    float4 v = xr[idx];
    ushort4 o;
    o.x = f2bf_rne(v.x); o.y = f2bf_rne(v.y);
    o.z = f2bf_rne(v.z); o.w = f2bf_rne(v.w);
    xb4[idx] = o;
#pragma unroll
    for (int e = 0; e < NE; ++e) {
      float4 g = g4[e * 512 + idx];
      acc[e] += v.x * g.x + v.y * g.y + v.z * g.z + v.w * g.w;
    }
  }
#pragma unroll
  for (int e = 0; e < NE; ++e) {
#pragma unroll
    for (int off = 32; off > 0; off >>= 1)
      acc[e] += __shfl_xor(acc[e], off, 64);
  }
  if (lane == 0) {
    float* lo = logits_out + (size_t)t * NE;
#pragma unroll
    for (int e = 0; e < NE; ++e) lo[e] = acc[e];
  }
}

// ---------------------------------------------------------------- bucket
// 8 blocks (one per expert) x 1024 threads. Recompute top-2 from exact fp32
// logits (top2 of logits == top2 of probs; renorm weight = 1/(1+exp(l1-l0))).
// Ballot-prefix compaction, LDS counter only — no contended global atomics.
__global__ __launch_bounds__(1024) void bucket_kernel(
    const float* __restrict__ logits, int* __restrict__ counts,
    int* __restrict__ btok, float* __restrict__ bwt) {
  const int e = blockIdx.x;
  __shared__ int lcount;
  if (threadIdx.x == 0) lcount = 0;
  __syncthreads();
  const int lane = threadIdx.x & 63;

  for (int base = 0; base < TOKENS; base += 1024) {
    int t = base + threadIdx.x;
    const float* lo = logits + (size_t)t * NE;
    float l[NE];
#pragma unroll
    for (int k = 0; k < NE; ++k) l[k] = lo[k];
    int i0 = 0; float b0 = l[0];
#pragma unroll
    for (int k = 1; k < NE; ++k) if (l[k] > b0) { b0 = l[k]; i0 = k; }
    int i1 = -1; float b1 = -3.4e38f;
#pragma unroll
    for (int k = 0; k < NE; ++k) if (k != i0 && l[k] > b1) { b1 = l[k]; i1 = k; }
    float w0 = 1.f / (1.f + __expf(b1 - b0));
    float w1 = 1.f - w0;
#pragma unroll
    for (int s = 0; s < 2; ++s) {
      int  ex = s ? i1 : i0;
      float w = s ? w1 : w0;
      bool p = (ex == e);
      unsigned long long mask = __ballot(p);
      int prefix = __popcll(mask & ((1ull << lane) - 1ull));
      int tot    = __popcll(mask);
      int wb = 0;
      if (lane == 0 && tot) wb = atomicAdd(&lcount, tot);  // LDS atomic, cheap
      wb = __shfl(wb, 0, 64);
      if (p) {
        btok[e * TOKENS + wb + prefix] = t;
        bwt [e * TOKENS + wb + prefix] = w;
      }
    }
  }
  __syncthreads();
  if (threadIdx.x == 0) counts[e * 32] = lcount;
}

// ---------------------------------------------------------------- MoE GEMM
// 1D grid with XCD-affinity swizzle: active region d<2048 maps d%8 == expert
// so each expert's weights stream through one XCD's L2, and the 16 rowtiles
// sharing a 512KB B-tile run temporally adjacent on that XCD.
__global__ __launch_bounds__(256, 4) void moe_gemm_kernel(
    const unsigned short* __restrict__ xb,
    const unsigned short* __restrict__ wb,
    const int* __restrict__ counts,
    const int* __restrict__ btok,
    const float* __restrict__ bwt,
    float* __restrict__ out) {
  int d = blockIdx.x;
  int e, coltile, rowtile;
  if (d < 2048) {
    e       = d & 7;          // XCD affinity (dispatch round-robins % 8)
    rowtile = (d >> 3) & 15;
    coltile = d >> 7;
  } else {
    int u = d - 2048;         // overflow region: experts with >2048 tokens
    rowtile = 16 + (u >> 7);
    coltile = (u & 127) >> 3;
    e       = u & 7;
  }
  const int cnt = counts[e * 32];
  if (rowtile * 128 >= cnt) return;

  __shared__ unsigned short As[128 * 64];   // 16 KB
  __shared__ unsigned short Bs[128 * 64];   // 16 KB  -> exactly 32 KB total

  const int tid  = threadIdx.x;
  const int wid  = tid >> 6;
  const int lane = tid & 63;

  // staging: 1024 16B slots/tile; LDS slot (row, cs) holds data chunk cs^(row&7)
  int a_off[4], b_off[4];
#pragma unroll
  for (int it = 0; it < 4; ++it) {
    int slot = wid * 256 + it * 64 + lane;
    int row  = slot >> 3;
    int ch   = (slot & 7) ^ (row & 7);
    int rc   = rowtile * 128 + row;
    rc = rc < cnt ? rc : cnt - 1;            // clamp pad rows
    a_off[it] = btok[e * TOKENS + rc] * HD + ch * 8;
    b_off[it] = (e * HD + coltile * 128 + row) * HD + ch * 8;
  }

  f32x4 acc[4][4];
#pragma unroll
  for (int i = 0; i < 4; ++i)
#pragma unroll
    for (int j = 0; j < 4; ++j) acc[i][j] = (f32x4){0.f, 0.f, 0.f, 0.f};

  const int quad = lane >> 4;
  const int mrow = lane & 15;
  const int wm2  = wid >> 1;
  const int wn2  = wid & 1;

  int a_rd[2][4], b_rd[2][4];
#pragma unroll
  for (int h = 0; h < 2; ++h)
#pragma unroll
    for (int i = 0; i < 4; ++i) {
      int ra = wm2 * 64 + i * 16 + mrow;
      a_rd[h][i] = ra * 64 + ((4 * h + quad) ^ (ra & 7)) * 8;
      int rb = wn2 * 64 + i * 16 + mrow;
      b_rd[h][i] = rb * 64 + ((4 * h + quad) ^ (rb & 7)) * 8;
    }

  for (int k0 = 0; k0 < HD; k0 += 64) {
#pragma unroll
    for (int it = 0; it < 4; ++it) {
      async_load16(xb + a_off[it] + k0, &As[(wid * 256 + it * 64) * 8]);
      async_load16(wb + b_off[it] + k0, &Bs[(wid * 256 + it * 64) * 8]);
    }
    __syncthreads();
#pragma unroll
    for (int h = 0; h < 2; ++h) {
      short8 fa[4], fb[4];
#pragma unroll
      for (int i = 0; i < 4; ++i) {
        fa[i] = *(const short8*)&As[a_rd[h][i]];
        fb[i] = *(const short8*)&Bs[b_rd[h][i]];
      }
#pragma unroll
      for (int i = 0; i < 4; ++i)
#pragma unroll
        for (int j = 0; j < 4; ++j)
          acc[i][j] = __builtin_amdgcn_mfma_f32_16x16x32_bf16(
              fa[i], fb[j], acc[i][j], 0, 0, 0);
    }
    __syncthreads();
  }

  // epilogue: D layout col=lane&15, row=quad*4+r (m89/m91). token id + weight
  // loaded directly (L1-hot small arrays); 2 atomic adds/element total.
#pragma unroll
  for (int i = 0; i < 4; ++i)
#pragma unroll
    for (int r = 0; r < 4; ++r) {
      int m  = wm2 * 64 + i * 16 + quad * 4 + r;
      int gm = rowtile * 128 + m;
      if (gm < cnt) {
        int   tok = btok[e * TOKENS + gm];
        float w   = bwt [e * TOKENS + gm];
        float* orow = out + (size_t)tok * HD + coltile * 128 + wn2 * 64 + mrow;
#pragma unroll
        for (int j = 0; j < 4; ++j)
          unsafeAtomicAdd(orow + j * 16, w * acc[i][j][r]);
      }
    }
}

// ---------------------------------------------------------------- launch
extern "C" void kernel_launch(void* const* d_in, const int* in_sizes, int n_in,
                              void* d_out, int out_size, void* d_ws, size_t ws_size,
                              hipStream_t stream) {
  const float* x  = (const float*)d_in[0];   // [8192, 2048]
  const float* gw = (const float*)d_in[1];   // [8, 2048]
  const float* ew = (const float*)d_in[2];   // [8, 2048, 2048]
  float* out = (float*)d_out;                // [8192*2048] ++ [8192*8]

  char* ws = (char*)d_ws;
  unsigned short* xb = (unsigned short*)ws;                      // 33,554,432 B
  unsigned short* wb = (unsigned short*)(ws + 33554432u);        // 67,108,864 B
  int*   counts = (int*)(ws + 100663296u);                       // 1,024 B
  int*   btok   = (int*)(ws + 100664320u);                       // 262,144 B
  float* bwt    = (float*)(ws + 100926464u);                     // 262,144 B

  float* logits = out + (size_t)TOKENS * HD;

  hipMemsetAsync(out, 0, (size_t)TOKENS * HD * sizeof(float), stream);
  convert_w_kernel<<<4096, 256, 0, stream>>>(ew, wb, NE * HD * HD / 8);
  router_kernel<<<TOKENS / 4, 256, 0, stream>>>(x, gw, xb, logits);
  bucket_kernel<<<NE, 1024, 0, stream>>>(logits, counts, btok, bwt);
  moe_gemm_kernel<<<8192, 256, 0, stream>>>(xb, wb, counts, btok, bwt, out);
}